// Round 2
// baseline (860.481 us; speedup 1.0000x reference)
//
#include <hip/hip_runtime.h>
#include <math.h>

#define ROWS_TOTAL 8192
#define KDIM 4096
#define NJ 25      // 4 pre + 4 post + 16 res + 1 ssq
#define KQ 1024    // k-range per block (quarter)
#define KC 64      // k per staged chunk
#define NC (KQ / KC)   // 16 chunks

// ------------------------------------------------------------------
// Kernel 1: partial dot products.
// grid = 512 blocks: 128 row-groups x 4 k-quarters. 512 threads (8 waves).
// Each wave handles 2 k-quads (wave, wave+8) per 64-k chunk; lane = row.
// x chunk transposed into LDS with XOR swizzle (row ^ (quad&7)) ->
// conflict-free b128 on both write and read phases.
// phi chunk staged into LDS; inner-loop phi reads are same-address
// broadcasts (conflict-free, lgkmcnt-pipelined).
// Pipeline: issue global loads for chunk c+1 -> compute chunk c ->
// ds_write c+1 into other buffer -> one barrier per chunk.
// ws layout: ws[quarter][j(25)][row(8192)]
// ------------------------------------------------------------------
__global__ __launch_bounds__(512, 4) void mhc_main(
    const float* __restrict__ x,
    const float* __restrict__ rmsw,
    const float* __restrict__ phi_pre,
    const float* __restrict__ phi_post,
    const float* __restrict__ phi_res,
    float* __restrict__ ws)
{
    // layout (float4 units): xb0[0..1023] xb1[1024..2047] pb0[2048..2447] pb1[2448..2847]
    // combine phase reuses the whole region (needs 11200 floats <= 11392)
    __shared__ __align__(16) float lds[11392];
    float4* const l4 = (float4*)lds;

    const int bid  = blockIdx.x;
    const int g    = bid >> 2;   // row group 0..127
    const int q    = bid & 3;    // k quarter 0..3
    const int t    = threadIdx.x;
    const int wave = t >> 6;     // 0..7
    const int lane = t & 63;

    float accp[4] = {0.f, 0.f, 0.f, 0.f};
    float acco[4] = {0.f, 0.f, 0.f, 0.f};
    float accr[16] = {0.f};
    float ssq = 0.f;

    // staging roles
    const int srow  = t >> 4;    // 0..31
    const int squad = t & 15;    // 0..15
    const float* xg = x + (size_t)(g * 64) * KDIM + q * KQ;
    const float4* ppre4 = (const float4*)phi_pre;
    const float4* ppo4  = (const float4*)phi_post;
    const float4* pres4 = (const float4*)phi_res;
    const float4* prw4  = (const float4*)rmsw;
    const int kq0 = q * KQ;      // global k base for this block

    float4 xr0 = {0,0,0,0}, xr1 = {0,0,0,0}, pr = {0,0,0,0};

    // issue global loads for chunk c into registers (in flight during compute)
    auto issue = [&](int c) {
        const int kb = c * KC;
        xr0 = *(const float4*)(xg + (size_t)srow        * KDIM + kb + squad * 4);
        xr1 = *(const float4*)(xg + (size_t)(srow + 32) * KDIM + kb + squad * 4);
        if (t < 64)       pr = ppre4[kq0 + kb + t];                       // pre, k=t
        else if (t < 128) pr = ppo4[kq0 + kb + (t - 64)];                 // post
        else if (t < 384) pr = pres4[(size_t)(kq0 + kb) * 4 + (t - 128)]; // res
        else if (t < 400) pr = prw4[(kq0 + kb) / 4 + (t - 384)];          // rmsw
    };
    // write staged registers into LDS buffer b
    auto commit = [&](int b) {
        float4* xb = l4 + b * 1024;
        float4* pb = l4 + 2048 + b * 400;
        xb[squad * 64 + (srow ^ (squad & 7))]        = xr0;
        xb[squad * 64 + ((srow + 32) ^ (squad & 7))] = xr1;
        if (t < 400) pb[t] = pr;
    };

    issue(0);
    commit(0);
    __syncthreads();

    for (int c = 0; c < NC; ++c) {
        const bool more = (c + 1 < NC);
        if (more) issue(c + 1);

        const int b = c & 1;
        const float4* xb = l4 + b * 1024;
        const float4* pb = l4 + 2048 + b * 400;
        #pragma unroll
        for (int u = 0; u < 2; ++u) {
            const int qd = wave + 8 * u;                     // quad 0..15
            const float4 xv = xb[qd * 64 + (lane ^ (qd & 7))];
            const float4 wv = pb[384 + qd];
            const float xa[4] = {xv.x, xv.y, xv.z, xv.w};
            const float wa[4] = {wv.x, wv.y, wv.z, wv.w};
            #pragma unroll
            for (int j = 0; j < 4; ++j) {
                const int kc = qd * 4 + j;
                const float xj = xa[j];
                const float xw = xj * wa[j];
                ssq = fmaf(xj, xj, ssq);
                const float4 pp = pb[kc];
                accp[0] = fmaf(xw, pp.x, accp[0]);
                accp[1] = fmaf(xw, pp.y, accp[1]);
                accp[2] = fmaf(xw, pp.z, accp[2]);
                accp[3] = fmaf(xw, pp.w, accp[3]);
                const float4 po = pb[64 + kc];
                acco[0] = fmaf(xw, po.x, acco[0]);
                acco[1] = fmaf(xw, po.y, acco[1]);
                acco[2] = fmaf(xw, po.z, acco[2]);
                acco[3] = fmaf(xw, po.w, acco[3]);
                #pragma unroll
                for (int ii = 0; ii < 4; ++ii) {
                    const float4 rr = pb[128 + kc * 4 + ii];
                    accr[ii * 4 + 0] = fmaf(xw, rr.x, accr[ii * 4 + 0]);
                    accr[ii * 4 + 1] = fmaf(xw, rr.y, accr[ii * 4 + 1]);
                    accr[ii * 4 + 2] = fmaf(xw, rr.z, accr[ii * 4 + 2]);
                    accr[ii * 4 + 3] = fmaf(xw, rr.w, accr[ii * 4 + 3]);
                }
            }
        }
        if (more) commit((c + 1) & 1);   // vmcnt drain happens here, after compute
        __syncthreads();
    }

    // cross-wave combine: waves 1..7 dump 25x64 partials, wave 0 sums + writes ws
    if (wave) {
        float* dst = lds + (wave - 1) * 1600;
        #pragma unroll
        for (int j = 0; j < 4; ++j)  dst[j * 64 + lane] = accp[j];
        #pragma unroll
        for (int j = 0; j < 4; ++j)  dst[(4 + j) * 64 + lane] = acco[j];
        #pragma unroll
        for (int j = 0; j < 16; ++j) dst[(8 + j) * 64 + lane] = accr[j];
        dst[24 * 64 + lane] = ssq;
    }
    __syncthreads();
    if (wave == 0) {
        float vals[NJ];
        #pragma unroll
        for (int j = 0; j < 4; ++j)  vals[j] = accp[j];
        #pragma unroll
        for (int j = 0; j < 4; ++j)  vals[4 + j] = acco[j];
        #pragma unroll
        for (int j = 0; j < 16; ++j) vals[8 + j] = accr[j];
        vals[24] = ssq;
        #pragma unroll
        for (int j = 0; j < NJ; ++j) {
            float s = vals[j];
            #pragma unroll
            for (int i = 0; i < 7; ++i)
                s += lds[i * 1600 + j * 64 + lane];
            ws[(size_t)q * (NJ * ROWS_TOTAL) + (size_t)j * ROWS_TOTAL + g * 64 + lane] = s;
        }
    }
}

// ------------------------------------------------------------------
// Kernel 2: combine 4 k-quarter partials, RMS scale, sigmoids, Sinkhorn.
// One thread per row; 128 blocks x 64 threads.
// ------------------------------------------------------------------
__device__ __forceinline__ float sigmoidf_(float z) {
    return 1.f / (1.f + __expf(-z));
}

__global__ __launch_bounds__(64) void mhc_epi(
    const float* __restrict__ ws,
    const float* __restrict__ b_pre,
    const float* __restrict__ b_post,
    const float* __restrict__ b_res,
    const float* __restrict__ a_pre,
    const float* __restrict__ a_post,
    const float* __restrict__ a_res,
    float* __restrict__ out)
{
    const int r = blockIdx.x * 64 + threadIdx.x;   // 0..8191
    float d[NJ];
    #pragma unroll
    for (int j = 0; j < NJ; ++j) {
        float s = 0.f;
        #pragma unroll
        for (int qq = 0; qq < 4; ++qq)
            s += ws[(size_t)qq * (NJ * ROWS_TOTAL) + (size_t)j * ROWS_TOTAL + r];
        d[j] = s;
    }
    const float scale = rsqrtf(d[24] * (1.0f / KDIM) + 1e-6f);
    const float ap  = a_pre[0] * scale;
    const float apo = a_post[0] * scale;
    const float ar  = a_res[0] * scale;

    float4 o0, o1;
    o0.x = sigmoidf_(fmaf(ap, d[0], b_pre[0]));
    o0.y = sigmoidf_(fmaf(ap, d[1], b_pre[1]));
    o0.z = sigmoidf_(fmaf(ap, d[2], b_pre[2]));
    o0.w = sigmoidf_(fmaf(ap, d[3], b_pre[3]));
    o1.x = 2.f * sigmoidf_(fmaf(apo, d[4], b_post[0]));
    o1.y = 2.f * sigmoidf_(fmaf(apo, d[5], b_post[1]));
    o1.z = 2.f * sigmoidf_(fmaf(apo, d[6], b_post[2]));
    o1.w = 2.f * sigmoidf_(fmaf(apo, d[7], b_post[3]));

    float m[16];
    #pragma unroll
    for (int i = 0; i < 16; ++i)
        m[i] = __expf(fmaf(ar, d[8 + i], b_res[i]));

    for (int it = 0; it < 20; ++it) {
        #pragma unroll
        for (int i = 0; i < 4; ++i) {           // row normalize
            const float s = m[4*i] + m[4*i+1] + m[4*i+2] + m[4*i+3];
            const float inv = 1.f / s;
            m[4*i] *= inv; m[4*i+1] *= inv; m[4*i+2] *= inv; m[4*i+3] *= inv;
        }
        #pragma unroll
        for (int i = 0; i < 4; ++i) {           // col normalize
            const float s = m[i] + m[4+i] + m[8+i] + m[12+i];
            const float inv = 1.f / s;
            m[i] *= inv; m[4+i] *= inv; m[8+i] *= inv; m[12+i] *= inv;
        }
    }

    float* o_pre  = out;
    float* o_post = out + 32768;
    float* o_res  = out + 65536;
    ((float4*)o_pre)[r]  = o0;
    ((float4*)o_post)[r] = o1;
    #pragma unroll
    for (int i = 0; i < 4; ++i)
        ((float4*)o_res)[r * 4 + i] = make_float4(m[4*i], m[4*i+1], m[4*i+2], m[4*i+3]);
}

extern "C" void kernel_launch(void* const* d_in, const int* in_sizes, int n_in,
                              void* d_out, int out_size, void* d_ws, size_t ws_size,
                              hipStream_t stream) {
    const float* x      = (const float*)d_in[0];
    const float* rmsw   = (const float*)d_in[1];
    const float* ppre   = (const float*)d_in[2];
    const float* ppost  = (const float*)d_in[3];
    const float* pres   = (const float*)d_in[4];
    const float* b_pre  = (const float*)d_in[5];
    const float* b_post = (const float*)d_in[6];
    const float* b_res  = (const float*)d_in[7];
    const float* a_pre  = (const float*)d_in[8];
    const float* a_post = (const float*)d_in[9];
    const float* a_res  = (const float*)d_in[10];
    float* ws  = (float*)d_ws;    // needs 4 * 25 * 8192 * 4 = 3.3 MB
    float* out = (float*)d_out;

    hipLaunchKernelGGL(mhc_main, dim3(512), dim3(512), 0, stream,
                       x, rmsw, ppre, ppost, pres, ws);
    hipLaunchKernelGGL(mhc_epi, dim3(128), dim3(64), 0, stream,
                       ws, b_pre, b_post, b_res, a_pre, a_post, a_res, out);
}

// Round 3
// 76.320 us; speedup vs baseline: 11.2747x; 11.2747x over previous
//
#include <hip/hip_runtime.h>
#include <math.h>

#define ROWS_TOTAL 8192
#define KDIM 4096
#define NJ 25          // 4 pre + 4 post + 16 res + 1 ssq
#define KQ 1024        // k-range per block (4-way split)
#define NS (KQ / 32)   // 32 K-steps of 32
#define BM 128         // rows per block (8 waves x 16 rows)
#define NTHREADS 512

typedef __attribute__((ext_vector_type(8))) short bf16x8;
typedef __attribute__((ext_vector_type(4))) float f32x4;

__device__ __forceinline__ unsigned short f2bf(float f) {
    union { float f; unsigned u; } v; v.f = f;
    unsigned r = (v.u + 0x7FFFu + ((v.u >> 16) & 1u)) >> 16;
    return (unsigned short)r;
}

union BF {
    uint4 u4;
    bf16x8 h;
};

// ------------------------------------------------------------------
// Kernel 1: bf16 MFMA projection + fp32 ssq.
// grid = 256 blocks: 64 row-groups x 4 k-quarters. 512 threads (8 waves).
// B (phi*w, 1024k x 32cols, cols: 0-3 pre, 4-7 post, 8-23 res, 24-31 pad)
// staged ONCE per block into LDS in MFMA-fragment order (64KB).
// A (x) loaded global->reg per K-step: wave w owns rows 16w..16w+15;
// lane l: row = 16w+(l&15), k = 32s + 8*(l>>4) + j  (2x dwordx4, coalesced).
// No barriers in main loop; ssq in fp32 VALU + shfl_xor reduce.
// ws layout: ws[quarter][j(25)][row(8192)]
// ------------------------------------------------------------------
__global__ __launch_bounds__(NTHREADS) void mhc_main(
    const float* __restrict__ x,
    const float* __restrict__ rmsw,
    const float* __restrict__ phi_pre,
    const float* __restrict__ phi_post,
    const float* __restrict__ phi_res,
    float* __restrict__ ws)
{
    __shared__ uint4 bfrag[NS * 2 * 64];   // 4096 frags * 16B = 64KB

    const int t    = threadIdx.x;
    const int wave = t >> 6;
    const int lane = t & 63;
    const int bid  = blockIdx.x;
    const int g    = bid >> 2;     // row group 0..63
    const int q    = bid & 3;      // k quarter 0..3
    const int kq0  = q * KQ;

    // ---- stage B fragments (one-time) ----
    #pragma unroll
    for (int f = 0; f < 8; ++f) {
        const int fid = f * NTHREADS + t;       // 0..4095
        const int s   = fid >> 7;               // K-step
        const int n   = (fid >> 6) & 1;         // col tile
        const int ln  = fid & 63;               // frag lane
        const int col = n * 16 + (ln & 15);
        const int kl  = s * 32 + 8 * (ln >> 4);
        unsigned short e[8];
        #pragma unroll
        for (int j = 0; j < 8; ++j) {
            const int k = kq0 + kl + j;
            float v = 0.f;
            if (col < 4)       v = rmsw[k] * phi_pre[k * 4 + col];
            else if (col < 8)  v = rmsw[k] * phi_post[k * 4 + (col - 4)];
            else if (col < 24) v = rmsw[k] * phi_res[k * 16 + (col - 8)];
            e[j] = f2bf(v);
        }
        uint4 pk;
        pk.x = (unsigned)e[0] | ((unsigned)e[1] << 16);
        pk.y = (unsigned)e[2] | ((unsigned)e[3] << 16);
        pk.z = (unsigned)e[4] | ((unsigned)e[5] << 16);
        pk.w = (unsigned)e[6] | ((unsigned)e[7] << 16);
        bfrag[(s * 2 + n) * 64 + ln] = pk;
    }
    __syncthreads();

    // ---- main loop ----
    const int row = g * BM + wave * 16 + (lane & 15);
    const float* xr = x + (size_t)row * KDIM + kq0 + 8 * (lane >> 4);

    f32x4 acc0 = {0.f, 0.f, 0.f, 0.f};
    f32x4 acc1 = {0.f, 0.f, 0.f, 0.f};
    float ssq = 0.f;

    #pragma unroll 4
    for (int s = 0; s < NS; ++s) {
        const float4 a0 = *(const float4*)(xr + 32 * s);
        const float4 a1 = *(const float4*)(xr + 32 * s + 4);
        ssq = fmaf(a0.x, a0.x, ssq);
        ssq = fmaf(a0.y, a0.y, ssq);
        ssq = fmaf(a0.z, a0.z, ssq);
        ssq = fmaf(a0.w, a0.w, ssq);
        ssq = fmaf(a1.x, a1.x, ssq);
        ssq = fmaf(a1.y, a1.y, ssq);
        ssq = fmaf(a1.z, a1.z, ssq);
        ssq = fmaf(a1.w, a1.w, ssq);
        BF af;
        af.u4.x = (unsigned)f2bf(a0.x) | ((unsigned)f2bf(a0.y) << 16);
        af.u4.y = (unsigned)f2bf(a0.z) | ((unsigned)f2bf(a0.w) << 16);
        af.u4.z = (unsigned)f2bf(a1.x) | ((unsigned)f2bf(a1.y) << 16);
        af.u4.w = (unsigned)f2bf(a1.z) | ((unsigned)f2bf(a1.w) << 16);
        BF b0, b1;
        b0.u4 = bfrag[(s * 2 + 0) * 64 + lane];
        b1.u4 = bfrag[(s * 2 + 1) * 64 + lane];
        acc0 = __builtin_amdgcn_mfma_f32_16x16x32_bf16(af.h, b0.h, acc0, 0, 0, 0);
        acc1 = __builtin_amdgcn_mfma_f32_16x16x32_bf16(af.h, b1.h, acc1, 0, 0, 0);
    }

    // ssq: combine the 4 k-offset groups (rows identical across l>>4)
    ssq += __shfl_xor(ssq, 16);
    ssq += __shfl_xor(ssq, 32);

    // ---- write partials: C/D layout col=lane&15, row=4*(lane>>4)+reg ----
    float* wsq = ws + (size_t)q * (NJ * ROWS_TOTAL);
    const int rbase = g * BM + wave * 16 + 4 * (lane >> 4);
    const int c0 = lane & 15;
    #pragma unroll
    for (int r = 0; r < 4; ++r)
        wsq[c0 * ROWS_TOTAL + rbase + r] = acc0[r];
    if (c0 < 8) {
        #pragma unroll
        for (int r = 0; r < 4; ++r)
            wsq[(16 + c0) * ROWS_TOTAL + rbase + r] = acc1[r];
    }
    if (lane < 16)
        wsq[24 * ROWS_TOTAL + g * BM + wave * 16 + lane] = ssq;
}

// ------------------------------------------------------------------
// Kernel 2: combine 4 k-quarter partials, RMS scale, sigmoids, Sinkhorn.
// One thread per row; 128 blocks x 64 threads.
// ------------------------------------------------------------------
__device__ __forceinline__ float sigmoidf_(float z) {
    return 1.f / (1.f + __expf(-z));
}

__global__ __launch_bounds__(64) void mhc_epi(
    const float* __restrict__ ws,
    const float* __restrict__ b_pre,
    const float* __restrict__ b_post,
    const float* __restrict__ b_res,
    const float* __restrict__ a_pre,
    const float* __restrict__ a_post,
    const float* __restrict__ a_res,
    float* __restrict__ out)
{
    const int r = blockIdx.x * 64 + threadIdx.x;   // 0..8191
    float d[NJ];
    #pragma unroll
    for (int j = 0; j < NJ; ++j) {
        float s = 0.f;
        #pragma unroll
        for (int qq = 0; qq < 4; ++qq)
            s += ws[(size_t)qq * (NJ * ROWS_TOTAL) + (size_t)j * ROWS_TOTAL + r];
        d[j] = s;
    }
    const float scale = rsqrtf(d[24] * (1.0f / KDIM) + 1e-6f);
    const float ap  = a_pre[0] * scale;
    const float apo = a_post[0] * scale;
    const float ar  = a_res[0] * scale;

    float4 o0, o1;
    o0.x = sigmoidf_(fmaf(ap, d[0], b_pre[0]));
    o0.y = sigmoidf_(fmaf(ap, d[1], b_pre[1]));
    o0.z = sigmoidf_(fmaf(ap, d[2], b_pre[2]));
    o0.w = sigmoidf_(fmaf(ap, d[3], b_pre[3]));
    o1.x = 2.f * sigmoidf_(fmaf(apo, d[4], b_post[0]));
    o1.y = 2.f * sigmoidf_(fmaf(apo, d[5], b_post[1]));
    o1.z = 2.f * sigmoidf_(fmaf(apo, d[6], b_post[2]));
    o1.w = 2.f * sigmoidf_(fmaf(apo, d[7], b_post[3]));

    float m[16];
    #pragma unroll
    for (int i = 0; i < 16; ++i)
        m[i] = __expf(fmaf(ar, d[8 + i], b_res[i]));

    for (int it = 0; it < 20; ++it) {
        #pragma unroll
        for (int i = 0; i < 4; ++i) {           // row normalize
            const float s = m[4*i] + m[4*i+1] + m[4*i+2] + m[4*i+3];
            const float inv = 1.f / s;
            m[4*i] *= inv; m[4*i+1] *= inv; m[4*i+2] *= inv; m[4*i+3] *= inv;
        }
        #pragma unroll
        for (int i = 0; i < 4; ++i) {           // col normalize
            const float s = m[i] + m[4+i] + m[8+i] + m[12+i];
            const float inv = 1.f / s;
            m[i] *= inv; m[4+i] *= inv; m[8+i] *= inv; m[12+i] *= inv;
        }
    }

    float* o_pre  = out;
    float* o_post = out + 32768;
    float* o_res  = out + 65536;
    ((float4*)o_pre)[r]  = o0;
    ((float4*)o_post)[r] = o1;
    #pragma unroll
    for (int i = 0; i < 4; ++i)
        ((float4*)o_res)[r * 4 + i] = make_float4(m[4*i], m[4*i+1], m[4*i+2], m[4*i+3]);
}

extern "C" void kernel_launch(void* const* d_in, const int* in_sizes, int n_in,
                              void* d_out, int out_size, void* d_ws, size_t ws_size,
                              hipStream_t stream) {
    const float* x      = (const float*)d_in[0];
    const float* rmsw   = (const float*)d_in[1];
    const float* ppre   = (const float*)d_in[2];
    const float* ppost  = (const float*)d_in[3];
    const float* pres   = (const float*)d_in[4];
    const float* b_pre  = (const float*)d_in[5];
    const float* b_post = (const float*)d_in[6];
    const float* b_res  = (const float*)d_in[7];
    const float* a_pre  = (const float*)d_in[8];
    const float* a_post = (const float*)d_in[9];
    const float* a_res  = (const float*)d_in[10];
    float* ws  = (float*)d_ws;    // needs 4 * 25 * 8192 * 4 = 3.3 MB
    float* out = (float*)d_out;

    hipLaunchKernelGGL(mhc_main, dim3(256), dim3(NTHREADS), 0, stream,
                       x, rmsw, ppre, ppost, pres, ws);
    hipLaunchKernelGGL(mhc_epi, dim3(128), dim3(64), 0, stream,
                       ws, b_pre, b_post, b_res, a_pre, a_post, a_res, out);
}